// Round 3
// baseline (1715.999 us; speedup 1.0000x reference)
//
#include <hip/hip_runtime.h>
#include <hip/hip_bf16.h>
#include <cstdint>
#include <cstddef>

// Problem constants
#define BATCH 64
#define LSEQ 200
#define HID 256
#define NH 8
#define DH 256            // per-head dim = HID
#define HD (NH*DH)        // 2048
#define MROWS (BATCH*LSEQ)   // 12800
#define EPS 1e-5f
#define CSCALE 0.09014195f   // (1/sqrt(256)) * log2(e), folded into Q projection

typedef unsigned short ushort_t;
typedef __attribute__((ext_vector_type(8))) short bf16x8;         // MFMA A/B frag (4 VGPR)
typedef __attribute__((ext_vector_type(8))) unsigned short u16x8; // 16B of bf16
typedef __attribute__((ext_vector_type(4))) float f32x4;          // MFMA C/D frag

__device__ __forceinline__ float b2f(ushort_t u) {
    union { unsigned int i; float f; } c; c.i = ((unsigned int)u) << 16; return c.f;
}
__device__ __forceinline__ ushort_t f2b(float f) {
    __hip_bfloat16 h = __float2bfloat16(f);
    union { __hip_bfloat16 h; ushort_t u; } c; c.h = h; return c.u;
}
__device__ __forceinline__ float to_f32(float x) { return x; }
__device__ __forceinline__ float to_f32(ushort_t x) { return b2f(x); }
__device__ __forceinline__ void store_val(float* p, float v) { *p = v; }
__device__ __forceinline__ void store_val(ushort_t* p, float v) { *p = f2b(v); }

// packed bf16 max / add on 8 elements
__device__ __forceinline__ u16x8 bmax8(u16x8 a, u16x8 b) {
    union U { u16x8 v; __hip_bfloat162 h[4]; };
    U ua, ub, r; ua.v = a; ub.v = b;
    #pragma unroll
    for (int i = 0; i < 4; ++i) r.h[i] = __hmax2(ua.h[i], ub.h[i]);
    return r.v;
}
__device__ __forceinline__ u16x8 badd8(u16x8 a, u16x8 b) {
    union U { u16x8 v; __hip_bfloat162 h[4]; };
    U ua, ub, r; ua.v = a; ub.v = b;
    #pragma unroll
    for (int i = 0; i < 4; ++i) r.h[i] = __hadd2(ua.h[i], ub.h[i]);
    return r.v;
}

// async global->LDS, 16 bytes per lane (LDS dest = wave-uniform base + lane*16)
__device__ __forceinline__ void gll16(const void* g, void* l) {
    __builtin_amdgcn_global_load_lds(
        (const __attribute__((address_space(1))) unsigned int*)g,
        (__attribute__((address_space(3))) unsigned int*)l, 16, 0, 0);
}

// ================= bf16 MFMA GEMM:  C[M,N] = A[M,K] @ Bt[N,K]^T + bias =================
// 128x128 tile, BK=32, 4 waves (2x2 of 64x64), global_load_lds staging, XOR-swizzled LDS.
// OMODE: 0 = row-major [m][n]; 1 = head-major [b][h][l][d]; 2 = transposed head-major
// [b][h][d][l] (row length LSEQ=200, 8B packed stores). Modes 1/2 require N==2048.
// SCALEC: multiply (acc+bias) by CSCALE (folds softmax scale*log2e into Q projection).
template<bool RELU, int OMODE, bool SCALEC>
__global__ __launch_bounds__(256) void gemm_bt(
    const ushort_t* __restrict__ A, const ushort_t* __restrict__ Bt,
    const float* __restrict__ bias, ushort_t* __restrict__ C,
    int M, int N, int K)
{
    __shared__ ushort_t As[128 * 32];
    __shared__ ushort_t Bs[128 * 32];
    const int t = threadIdx.x;
    const int m0 = blockIdx.y * 128, n0 = blockIdx.x * 128;
    const int wave = t >> 6, lane = t & 63;
    const int l15 = lane & 15, lq = lane >> 4;
    const int wr = wave >> 1, wc = wave & 1;

    f32x4 acc[4][4];
    #pragma unroll
    for (int i = 0; i < 4; ++i)
        #pragma unroll
        for (int j = 0; j < 4; ++j) acc[i][j] = (f32x4){0.f, 0.f, 0.f, 0.f};

    for (int k0 = 0; k0 < K; k0 += 32) {
        __syncthreads();
        #pragma unroll
        for (int i = 0; i < 2; ++i) {      // stage A (2 x 16B per thread)
            int li = i * 256 + t;
            int ml = li >> 2, cp = li & 3;
            int cg = cp ^ ((ml ^ (ml >> 2)) & 3);
            gll16(A + (size_t)(m0 + ml) * K + k0 + cg * 8, &As[li * 8]);
        }
        #pragma unroll
        for (int i = 0; i < 2; ++i) {      // stage B
            int li = i * 256 + t;
            int nl = li >> 2, cp = li & 3;
            int cg = cp ^ ((nl ^ (nl >> 2)) & 3);
            gll16(Bt + (size_t)(n0 + nl) * K + k0 + cg * 8, &Bs[li * 8]);
        }
        __syncthreads();
        bf16x8 af[4], bfr[4];
        #pragma unroll
        for (int i = 0; i < 4; ++i) {
            int r = wr * 64 + i * 16 + l15;
            int pc = lq ^ ((r ^ (r >> 2)) & 3);
            af[i] = *(const bf16x8*)&As[r * 32 + pc * 8];
        }
        #pragma unroll
        for (int j = 0; j < 4; ++j) {
            int r = wc * 64 + j * 16 + l15;
            int pc = lq ^ ((r ^ (r >> 2)) & 3);
            bfr[j] = *(const bf16x8*)&Bs[r * 32 + pc * 8];
        }
        #pragma unroll
        for (int i = 0; i < 4; ++i)
            #pragma unroll
            for (int j = 0; j < 4; ++j)
                acc[i][j] = __builtin_amdgcn_mfma_f32_16x16x32_bf16(af[i], bfr[j], acc[i][j], 0, 0, 0);
    }
    // epilogue: C layout col=lane&15, row=4*quad+e
    if (OMODE == 2) {
        #pragma unroll
        for (int i = 0; i < 4; ++i) {
            int mbase = m0 + wr * 64 + i * 16 + 4 * lq;         // 4-aligned; 200%4==0
            int bb = (int)(((unsigned)mbase * 5243u) >> 20);    // mbase/200
            int ll = mbase - bb * 200;
            #pragma unroll
            for (int j = 0; j < 4; ++j) {
                int n = n0 + wc * 64 + j * 16 + l15;
                float bsv = bias[n];
                ushort4 o4;
                o4.x = f2b(acc[i][j][0] + bsv); o4.y = f2b(acc[i][j][1] + bsv);
                o4.z = f2b(acc[i][j][2] + bsv); o4.w = f2b(acc[i][j][3] + bsv);
                size_t addr = ((size_t)(bb * NH + (n >> 8)) * 256 + (n & 255)) * LSEQ + ll;
                *(ushort4*)&C[addr] = o4;
            }
        }
    } else {
        #pragma unroll
        for (int i = 0; i < 4; ++i) {
            #pragma unroll
            for (int e = 0; e < 4; ++e) {
                int m = m0 + wr * 64 + i * 16 + 4 * lq + e;
                #pragma unroll
                for (int j = 0; j < 4; ++j) {
                    int n = n0 + wc * 64 + j * 16 + l15;
                    float v = acc[i][j][e] + bias[n];
                    if (RELU) v = fmaxf(v, 0.f);
                    if (SCALEC) v *= CSCALE;
                    if (OMODE == 1) {
                        int bb = (int)(((unsigned)m * 5243u) >> 20);
                        int ll = m - bb * 200;
                        size_t addr = ((((size_t)(bb * NH + (n >> 8))) * LSEQ + ll) << 8) + (n & 255);
                        C[addr] = f2b(v);
                    } else {
                        C[(size_t)m * N + n] = f2b(v);
                    }
                }
            }
        }
    }
}

// ================= fused area-attention v14 (double-buffered pooling pipeline) =======
// v13 (in-register P, operand-swapped QK^T, sigma-permuted V) + pipelined staging:
// Ks/Vs double-buffered (2x32KB each, 128KB LDS, 1 block/CU unchanged -- occupancy is
// register-bound at ~190 unified regs, so LDS is free). Each step: {issue next-class
// global loads -> compute(cur buf) -> pool-RMW cur->next buf -> ONE barrier}. The RMW
// reads class-c state from buf A and writes class-c+1 into buf B, so a single barrier
// per step is race-free (A's readers finish before A is rewritten 2 steps later).
// Staging VALU + L2 latency now hides under MFMA via inter-wave drift between barriers.
// V tile is register-cached (vc[5], 20 VGPR) and loaded once per 64-m tile (was 5x).
// Barriers: 16 (was 32).
__global__ __launch_bounds__(512, 2) void attn_mfma14(
    const ushort_t* __restrict__ Q, const ushort_t* __restrict__ Khm,
    const ushort_t* __restrict__ Vt, ushort_t* __restrict__ O)  // O may alias Q
{
    const int id = blockIdx.x;
    const int xcd = id & 7, slot_ = id >> 3;    // 1024 blocks: 8 xcd x 128 slots
    const int qt = slot_ & 1;
    const int bh = ((slot_ >> 1) << 3) + xcd;   // both q-blocks of bh share an XCD
    const int b = bh >> 3, h = bh & 7;
    const int q0 = qt * 128;
    const int t = threadIdx.x;
    const int wave = t >> 6, lane = t & 63;
    const int l15 = lane & 15, lq = lane >> 4;

    __shared__ ushort_t Ks[2 * 64 * 256];  // pooled K [m][d], chunk ^ (m&15), 2x32 KB
    __shared__ ushort_t Vs[2 * 256 * 64];  // pooled V [d][kpos], chunk ^ (d&7), 2x32 KB

    const ushort_t* kbh = Khm + (size_t)bh * LSEQ * DH;
    const ushort_t* vtb = Vt + (size_t)bh * DH * LSEQ;   // [d][l]
    const ushort_t* qbh = Q + ((size_t)b * LSEQ) * HD + h * DH;
    const int qrow = q0 + wave * 16 + l15;

    // Q fragments; pre-scaled by CSCALE in GEMM. B-operand of swapped QK^T.
    bf16x8 qf[8];
    if (qrow < LSEQ) {
        const ushort_t* qp = qbh + (size_t)qrow * HD + 8 * lq;
        #pragma unroll
        for (int g = 0; g < 8; ++g) qf[g] = *(const bf16x8*)(qp + 32 * g);
    } else {
        bf16x8 zf = {0,0,0,0,0,0,0,0};
        #pragma unroll
        for (int g = 0; g < 8; ++g) qf[g] = zf;
    }

    f32x4 oacc[16];
    #pragma unroll
    for (int i = 0; i < 16; ++i) oacc[i] = (f32x4){0.f, 0.f, 0.f, 0.f};
    float l_part = 0.f;

    // staging roles for 512 threads
    const int dc = t & 31, mb = t >> 5;      // K: lane->d-chunk, thread->4 m's (mb 0..15)
    const int vd = t >> 1, vh = t & 1;       // V: thread -> d row, half (4 chunks each)

    // staging register state (function scope so lambdas capture; all static-indexed)
    u16x8 vc[5];       // V tile cache: elems [st0+vh*32 .. +39] of row vd
    u16x8 kf[4];       // next-class K rows
    u16x8 ktail[5];    // tail K rows (mb<8 only)
    u16x8 v0t;         // tail V elems 192..199

    auto loadK = [&](int row0) {
        #pragma unroll
        for (int k4 = 0; k4 < 4; ++k4)
            kf[k4] = *(const u16x8*)(kbh + (size_t)(row0 + mb + 16 * k4) * DH + dc * 8);
    };
    auto loadV = [&](int s0) {
        const ushort_t* vrow = vtb + (size_t)vd * LSEQ + s0 + vh * 32;
        #pragma unroll
        for (int c = 0; c < 5; ++c) vc[c] = *(const u16x8*)(vrow + c * 8);
    };
    auto stageK_dir = [&](int bn) {
        #pragma unroll
        for (int k4 = 0; k4 < 4; ++k4) {
            int m = mb + 16 * k4;
            *(u16x8*)&Ks[bn + m * 256 + ((dc ^ (m & 15)) * 8)] = kf[k4];
        }
    };
    auto stageK_rmw = [&](int bo, int bn) {
        #pragma unroll
        for (int k4 = 0; k4 < 4; ++k4) {
            int m = mb + 16 * k4;
            int off = m * 256 + ((dc ^ (m & 15)) * 8);
            *(u16x8*)&Ks[bn + off] = bmax8(*(const u16x8*)&Ks[bo + off], kf[k4]);
        }
    };
    auto stageV_dir = [&](int bn) {
        #pragma unroll
        for (int cl = 0; cl < 4; ++cl) {
            const int cg = vh * 4 + cl;
            const int kc = (cg >> 2) * 4 + (cg & 1) * 2;
            const int par4 = ((cg >> 1) & 1) * 4;
            union VHd { u16x8 v; ushort4 hh[2]; } nv;
            nv.v = vc[cl];
            *(ushort4*)&Vs[bn + vd * 64 + ((kc ^ (vd & 7)) * 8) + par4] = nv.hh[0];
            *(ushort4*)&Vs[bn + vd * 64 + (((kc + 1) ^ (vd & 7)) * 8) + par4] = nv.hh[1];
        }
    };

    // one MFMA+softmax+PV compute step over buffer at offset bo
    auto step = [&](int bo, bool tail) {
        f32x4 sacc[4];
        __builtin_amdgcn_s_setprio(1);
        #pragma unroll
        for (int ms = 0; ms < 4; ++ms) {
            f32x4 s = (f32x4){0.f, 0.f, 0.f, 0.f};
            const int row = ms * 16 + l15;
            #pragma unroll
            for (int g = 0; g < 8; ++g) {
                const int phys = (lq + 4 * g) ^ l15;
                s = __builtin_amdgcn_mfma_f32_16x16x32_bf16(
                        *(const bf16x8*)&Ks[bo + row * 256 + phys * 8], qf[g], s, 0, 0, 0);
            }
            sacc[ms] = s;
        }
        __builtin_amdgcn_s_setprio(0);
        unsigned int w[8];
        #pragma unroll
        for (int ms = 0; ms < 4; ++ms) {
            float pj[4];
            #pragma unroll
            for (int e = 0; e < 4; ++e) {
                float sv = sacc[ms][e];
                if (tail) {  // slot = 8*cls + off, valid iff off <= 7-cls, cls <= 4
                    const int slot = ms * 16 + 4 * lq + e;
                    if (((slot & 7) > 7 - (slot >> 3)) || ((slot >> 3) > 4)) sv = -1e30f;
                }
                float pe = __builtin_exp2f(sv);
                l_part += pe;
                pj[e] = pe;
            }
            asm("v_cvt_pk_bf16_f32 %0, %1, %2" : "=v"(w[2*ms])   : "v"(pj[0]), "v"(pj[1]));
            asm("v_cvt_pk_bf16_f32 %0, %1, %2" : "=v"(w[2*ms+1]) : "v"(pj[2]), "v"(pj[3]));
        }
        union FR { unsigned int u[4]; bf16x8 v; };
        FR f0, f1;
        f0.u[0] = w[0]; f0.u[1] = w[1]; f0.u[2] = w[2]; f0.u[3] = w[3];
        f1.u[0] = w[4]; f1.u[1] = w[5]; f1.u[2] = w[6]; f1.u[3] = w[7];
        const bf16x8 pf0 = f0.v, pf1 = f1.v;
        __builtin_amdgcn_s_setprio(1);
        #pragma unroll
        for (int dt = 0; dt < 16; ++dt) {
            const int d = dt * 16 + l15;
            const int c0 = lq ^ (d & 7);
            const int c1 = (lq + 4) ^ (d & 7);
            oacc[dt] = __builtin_amdgcn_mfma_f32_16x16x32_bf16(
                           pf0, *(const bf16x8*)&Vs[bo + d * 64 + c0 * 8], oacc[dt], 0, 0, 0);
            oacc[dt] = __builtin_amdgcn_mfma_f32_16x16x32_bf16(
                           pf1, *(const bf16x8*)&Vs[bo + d * 64 + c1 * 8], oacc[dt], 0, 0, 0);
        }
        __builtin_amdgcn_s_setprio(0);
    };

// per-step body: A) issue next loads  B) compute(cur)  C) stage(next)  D) barrier.
#define ATTN_STEP(CLS)                                                           \
    {                                                                            \
        const int bo = pbuf * 16384, bn = bo ^ 16384;                            \
        const bool lastS = ((CLS) == 4) && (ti == 2);                            \
        if ((CLS) < 4) {                                                         \
            loadK(st0 + (CLS) + 1);                                              \
        } else if (!lastS) {                                                     \
            loadK(st0 + 64);                                                     \
            loadV(st0 + 64);                                                     \
        } else {                                                                 \
            if (mb < 8) {                                                        \
                _Pragma("unroll")                                                \
                for (int k8 = 0; k8 < 5; ++k8)                                   \
                    if (mb + k8 <= 7)                                            \
                        ktail[k8] = *(const u16x8*)(kbh + (size_t)(192 + mb + k8) * DH + dc * 8); \
            }                                                                    \
            v0t = *(const u16x8*)(vtb + (size_t)vd * LSEQ + 192);                \
        }                                                                        \
        step(bo, false);                                                         \
        if ((CLS) < 4) {                                                         \
            stageK_rmw(bo, bn);                                                  \
            _Pragma("unroll")                                                    \
            for (int cl = 0; cl < 4; ++cl) {                                     \
                const int cg = vh * 4 + cl;                                      \
                const int kc = (cg >> 2) * 4 + (cg & 1) * 2;                     \
                const int par4 = ((cg >> 1) & 1) * 4;                            \
                const int olo = vd * 64 + ((kc ^ (vd & 7)) * 8) + par4;          \
                const int ohi = vd * 64 + (((kc + 1) ^ (vd & 7)) * 8) + par4;    \
                u16x8 sh;                                                        \
                _Pragma("unroll")                                                \
                for (int j = 0; j < 8; ++j)                                      \
                    sh[j] = (j + (CLS) + 1 < 8) ? vc[cl][j + (CLS) + 1]          \
                                                : vc[cl + 1][j + (CLS) + 1 - 8]; \
                union VHm { u16x8 v; ushort4 hh[2]; } curv, nv;                  \
                curv.hh[0] = *(const ushort4*)&Vs[bo + olo];                     \
                curv.hh[1] = *(const ushort4*)&Vs[bo + ohi];                     \
                nv.v = badd8(curv.v, sh);                                        \
                *(ushort4*)&Vs[bn + olo] = nv.hh[0];                             \
                *(ushort4*)&Vs[bn + ohi] = nv.hh[1];                             \
            }                                                                    \
        } else if (!lastS) {                                                     \
            stageK_dir(bn);                                                      \
            stageV_dir(bn);                                                      \
        } else {                                                                 \
            if (mb < 8) {                                                        \
                u16x8 krun = ktail[0];                                           \
                const u16x8 kz = {0,0,0,0,0,0,0,0};                              \
                _Pragma("unroll")                                                \
                for (int k8 = 0; k8 < 8; ++k8) {                                 \
                    const bool vv = (k8 <= 4) && (mb <= 7 - k8);                 \
                    if (k8 > 0 && k8 <= 4 && vv)                                 \
                        krun = bmax8(krun, ktail[(k8 <= 4) ? k8 : 0]);           \
                    const int slot = k8 * 8 + mb;                                \
                    *(u16x8*)&Ks[bn + slot * 256 + ((dc ^ (slot & 15)) * 8)] =   \
                        vv ? krun : kz;                                          \
                }                                                                \
            }                                                                    \
            {                                                                    \
                float fv[8];                                                     \
                _Pragma("unroll")                                                \
                for (int e = 0; e < 8; ++e) fv[e] = b2f(v0t[e]);                 \
                _Pragma("unroll")                                                \
                for (int cl = 0; cl < 4; ++cl) {                                 \
                    const int c = vh * 4 + cl;                                   \
                    union VHt { u16x8 v; ushort4 hh[2]; } ov;                    \
                    _Pragma("unroll")                                            \
                    for (int j = 0; j < 8; ++j) ov.v[j] = 0;                     \
                    if (c <= 4) {                                                \
                        _Pragma("unroll")                                        \
                        for (int j = 0; j < 8; ++j) {                            \
                            if (j <= 7 - c) {                                    \
                                float a = 0.f;                                   \
                                _Pragma("unroll")                                \
                                for (int u = 0; u <= 4; ++u)                     \
                                    if (u <= c) a += fv[j + u];                  \
                                ov.v[j] = f2b(a);                                \
                            }                                                    \
                        }                                                        \
                    }                                                            \
                    const int kc = (c >> 2) * 4 + (c & 1) * 2;                   \
                    const int par4 = ((c >> 1) & 1) * 4;                         \
                    *(ushort4*)&Vs[bn + vd * 64 + ((kc ^ (vd & 7)) * 8) + par4] = ov.hh[0]; \
                    *(ushort4*)&Vs[bn + vd * 64 + (((kc + 1) ^ (vd & 7)) * 8) + par4] = ov.hh[1]; \
                }                                                                \
            }                                                                    \
        }                                                                        \
        __syncthreads();                                                         \
        pbuf ^= 1;                                                               \
    }

    // prologue: stage tile0/class0 into buffer 0
    int pbuf = 0;
    loadV(0);
    loadK(0);
    stageK_dir(0);
    stageV_dir(0);
    __syncthreads();

    for (int ti = 0; ti < 3; ++ti) {
        const int st0 = ti * 64;
        ATTN_STEP(0)
        ATTN_STEP(1)
        ATTN_STEP(2)
        ATTN_STEP(3)
        ATTN_STEP(4)
    }
    // final compute: fused tail classes (staged by step 14 into buffer pbuf)
    step(pbuf * 16384, true);
#undef ATTN_STEP

    // epilogue: l for q-row l15 -> reduce over the 4 lq groups, invert, redistribute
    l_part += __shfl_xor(l_part, 16);
    l_part += __shfl_xor(l_part, 32);
    const float inv = 1.f / l_part;

    ushort_t* ob = O + ((size_t)b * LSEQ) * HD + h * DH;
    #pragma unroll
    for (int e = 0; e < 4; ++e) {
        const int q = q0 + wave * 16 + 4 * lq + e;
        const float linv = __shfl(inv, 4 * lq + e);
        if (q < LSEQ) {
            #pragma unroll
            for (int dt = 0; dt < 16; ++dt)
                ob[(size_t)q * HD + dt * 16 + l15] = f2b(oacc[dt][e] * linv);
        }
    }
}

// ================= residual + LayerNorm: Out = LN(bf16 X + R) =================
template<typename TR, typename TO>
__global__ __launch_bounds__(256) void residual_ln(
    const ushort_t* __restrict__ X, const TR* __restrict__ R, TO* __restrict__ Out)
{
    const int row = blockIdx.x;
    const int t = threadIdx.x;
    const size_t base = (size_t)row * HID;
    float v = b2f(X[base + t]) + to_f32(R[base + t]);
    float s = v, q = v * v;
    #pragma unroll
    for (int o = 32; o > 0; o >>= 1) {
        s += __shfl_xor(s, o, 64);
        q += __shfl_xor(q, o, 64);
    }
    __shared__ float ss[4], sq[4];
    const int wave = t >> 6, lane = t & 63;
    if (lane == 0) { ss[wave] = s; sq[wave] = q; }
    __syncthreads();
    s = ss[0] + ss[1] + ss[2] + ss[3];
    q = sq[0] + sq[1] + sq[2] + sq[3];
    float mean = s * (1.f / HID);
    float var  = q * (1.f / HID) - mean * mean;
    store_val(&Out[base + t], (v - mean) * rsqrtf(var + EPS));
}

// ================= converts =================
__global__ __launch_bounds__(256) void cvt_f32_bf16(const float* __restrict__ in,
                                                    ushort_t* __restrict__ out) {
    const int i = (blockIdx.x * 256 + threadIdx.x) * 4;
    float4 v = *(const float4*)(in + i);
    ushort4 o;
    o.x = f2b(v.x); o.y = f2b(v.y); o.z = f2b(v.z); o.w = f2b(v.w);
    *(ushort4*)(out + i) = o;
}

// W[K,N] f32 -> Wt[N,K] bf16
__global__ __launch_bounds__(256) void wtrans(const float* __restrict__ W,
                                              ushort_t* __restrict__ Wt, int K, int N) {
    __shared__ float tile[32][33];
    const int t = threadIdx.x;
    const int tx = t & 31, ty = t >> 5;
    const int n0 = blockIdx.x * 32, k0 = blockIdx.y * 32;
    #pragma unroll
    for (int s = 0; s < 4; ++s)
        tile[ty + 8 * s][tx] = W[(size_t)(k0 + ty + 8 * s) * N + n0 + tx];
    __syncthreads();
    #pragma unroll
    for (int s = 0; s < 4; ++s)
        Wt[(size_t)(n0 + ty + 8 * s) * K + k0 + tx] = f2b(tile[tx][ty + 8 * s]);
}

// ================= launch =================
extern "C" void kernel_launch(void* const* d_in, const int* in_sizes, int n_in,
                              void* d_out, int out_size, void* d_ws, size_t ws_size,
                              hipStream_t stream) {
    const float* hidden = (const float*)d_in[1];
    const float* Wq = (const float*)d_in[2];  const float* bq = (const float*)d_in[3];
    const float* Wk = (const float*)d_in[4];  const float* bk = (const float*)d_in[5];
    const float* Wv = (const float*)d_in[6];  const float* bv = (const float*)d_in[7];
    const float* Wo = (const float*)d_in[8];  const float* bo = (const float*)d_in[9];
    const float* W1 = (const float*)d_in[10]; const float* b1 = (const float*)d_in[11];
    const float* W2 = (const float*)d_in[12]; const float* b2 = (const float*)d_in[13];
    float* out = (float*)d_out;

    constexpr size_t SZ_BF   = (size_t)MROWS * HD * 2;      // 52,428,800
    constexpr size_t SZ_HBF  = (size_t)MROWS * HID * 2;     // 6,553,600
    constexpr size_t SZ_WQKV = (size_t)HID * HD * 2;        // 1,048,576
    constexpr size_t SZ_W12  = (size_t)HID * 4 * HID * 2;   // 524,288
    char* ws = (char*)d_ws;
    size_t off = 0;
    ushort_t* kb   = (ushort_t*)(ws + off); off += SZ_BF;   // K head-major [b,h][l][d]
    ushort_t* vt   = (ushort_t*)(ws + off); off += SZ_BF;   // V transposed  [b,h][d][l]
    ushort_t* qo   = (ushort_t*)(ws + off); off += SZ_BF;   // q / attn-out / ffn1
    ushort_t* hb   = (ushort_t*)(ws + off); off += SZ_HBF;  // hidden bf16
    ushort_t* at1  = (ushort_t*)(ws + off); off += SZ_HBF;
    ushort_t* at2  = (ushort_t*)(ws + off); off += SZ_HBF;
    ushort_t* proj = (ushort_t*)(ws + off); off += SZ_HBF;
    ushort_t* WtQ  = (ushort_t*)(ws + off); off += SZ_WQKV;
    ushort_t* WtK  = (ushort_t*)(ws + off); off += SZ_WQKV;
    ushort_t* WtV  = (ushort_t*)(ws + off); off += SZ_WQKV;
    ushort_t* WtO  = (ushort_t*)(ws + off); off += SZ_WQKV;
    ushort_t* Wt1  = (ushort_t*)(ws + off); off += SZ_W12;
    ushort_t* Wt2  = (ushort_t*)(ws + off); off += SZ_W12;
    if (ws_size < off) return;  // total == 188,743,680 B (same as passing R3/R5-R11)
    ushort_t* ffn1 = qo;        // alias: qo free after out-proj2

    dim3 blk(256);
    cvt_f32_bf16<<<MROWS * HID / 1024, blk, 0, stream>>>(hidden, hb);
    wtrans<<<dim3(HD / 32, HID / 32), blk, 0, stream>>>(Wq, WtQ, HID, HD);
    wtrans<<<dim3(HD / 32, HID / 32), blk, 0, stream>>>(Wk, WtK, HID, HD);
    wtrans<<<dim3(HD / 32, HID / 32), blk, 0, stream>>>(Wv, WtV, HID, HD);
    wtrans<<<dim3(HID / 32, HD / 32), blk, 0, stream>>>(Wo, WtO, HD, HID);
    wtrans<<<dim3(4 * HID / 32, HID / 32), blk, 0, stream>>>(W1, Wt1, HID, 4 * HID);
    wtrans<<<dim3(HID / 32, 4 * HID / 32), blk, 0, stream>>>(W2, Wt2, 4 * HID, HID);

    const dim3 gProj(HD / 128, MROWS / 128);
    const dim3 gOut(HID / 128, MROWS / 128);
    const dim3 gF1(4 * HID / 128, MROWS / 128);

    // K head-major; V transposed head-major (shared by both MHAs)
    gemm_bt<false, 1, false><<<gProj, blk, 0, stream>>>(hb, WtK, bk, kb, MROWS, HD, HID);
    gemm_bt<false, 2, false><<<gProj, blk, 0, stream>>>(hb, WtV, bv, vt, MROWS, HD, HID);

    // MHA1 (Q pre-scaled by CSCALE)
    gemm_bt<false, 0, true><<<gProj, blk, 0, stream>>>(hb, WtQ, bq, qo, MROWS, HD, HID);
    attn_mfma14<<<2 * BATCH * NH, 512, 0, stream>>>(qo, kb, vt, qo);
    gemm_bt<false, 0, false><<<gOut, blk, 0, stream>>>(qo, WtO, bo, proj, MROWS, HID, HD);
    residual_ln<float, ushort_t><<<MROWS, blk, 0, stream>>>(proj, hidden, at1);

    // MHA2 (q from attn1; pooled K/V rebuilt from same kb/vt)
    gemm_bt<false, 0, true><<<gProj, blk, 0, stream>>>(at1, WtQ, bq, qo, MROWS, HD, HID);
    attn_mfma14<<<2 * BATCH * NH, 512, 0, stream>>>(qo, kb, vt, qo);
    gemm_bt<false, 0, false><<<gOut, blk, 0, stream>>>(qo, WtO, bo, proj, MROWS, HID, HD);
    residual_ln<ushort_t, ushort_t><<<MROWS, blk, 0, stream>>>(proj, at1, at2);

    // FFN
    gemm_bt<true, 0, false><<<gF1, blk, 0, stream>>>(at2, Wt1, b1, ffn1, MROWS, 4 * HID, HID);
    gemm_bt<false, 0, false><<<gOut, blk, 0, stream>>>(ffn1, Wt2, b2, proj, MROWS, HID, 4 * HID);
    residual_ln<ushort_t, float><<<MROWS, blk, 0, stream>>>(proj, at2, out);
}

// Round 4
// 1671.835 us; speedup vs baseline: 1.0264x; 1.0264x over previous
//
#include <hip/hip_runtime.h>
#include <hip/hip_bf16.h>
#include <cstdint>
#include <cstddef>

// Problem constants
#define BATCH 64
#define LSEQ 200
#define HID 256
#define NH 8
#define DH 256            // per-head dim = HID
#define HD (NH*DH)        // 2048
#define MROWS (BATCH*LSEQ)   // 12800
#define EPS 1e-5f
#define CSCALE 0.09014195f   // (1/sqrt(256)) * log2(e), folded into Q projection

typedef unsigned short ushort_t;
typedef __attribute__((ext_vector_type(8))) short bf16x8;         // MFMA A/B frag (4 VGPR)
typedef __attribute__((ext_vector_type(8))) unsigned short u16x8; // 16B of bf16
typedef __attribute__((ext_vector_type(4))) float f32x4;          // MFMA C/D frag

__device__ __forceinline__ float b2f(ushort_t u) {
    union { unsigned int i; float f; } c; c.i = ((unsigned int)u) << 16; return c.f;
}
__device__ __forceinline__ ushort_t f2b(float f) {
    __hip_bfloat16 h = __float2bfloat16(f);
    union { __hip_bfloat16 h; ushort_t u; } c; c.h = h; return c.u;
}
__device__ __forceinline__ float to_f32(float x) { return x; }
__device__ __forceinline__ float to_f32(ushort_t x) { return b2f(x); }
__device__ __forceinline__ void store_val(float* p, float v) { *p = v; }
__device__ __forceinline__ void store_val(ushort_t* p, float v) { *p = f2b(v); }

// packed bf16 max / add on 8 elements
__device__ __forceinline__ u16x8 bmax8(u16x8 a, u16x8 b) {
    union U { u16x8 v; __hip_bfloat162 h[4]; };
    U ua, ub, r; ua.v = a; ub.v = b;
    #pragma unroll
    for (int i = 0; i < 4; ++i) r.h[i] = __hmax2(ua.h[i], ub.h[i]);
    return r.v;
}
__device__ __forceinline__ u16x8 badd8(u16x8 a, u16x8 b) {
    union U { u16x8 v; __hip_bfloat162 h[4]; };
    U ua, ub, r; ua.v = a; ub.v = b;
    #pragma unroll
    for (int i = 0; i < 4; ++i) r.h[i] = __hadd2(ua.h[i], ub.h[i]);
    return r.v;
}

// async global->LDS, 16 bytes per lane (LDS dest = wave-uniform base + lane*16)
__device__ __forceinline__ void gll16(const void* g, void* l) {
    __builtin_amdgcn_global_load_lds(
        (const __attribute__((address_space(1))) unsigned int*)g,
        (__attribute__((address_space(3))) unsigned int*)l, 16, 0, 0);
}

// ================= bf16 MFMA GEMM:  C[M,N] = A[M,K] @ Bt[N,K]^T + bias =================
// 128x128 tile, BK=32, 4 waves (2x2 of 64x64), global_load_lds staging, XOR-swizzled LDS.
// OMODE: 0 = row-major [m][n]; 1 = head-major [b][h][l][d]; 2 = transposed head-major
// [b][h][d][l] (row length LSEQ=200, 8B packed stores). Modes 1/2 require N==2048.
// SCALEC: multiply (acc+bias) by CSCALE (folds softmax scale*log2e into Q projection).
template<bool RELU, int OMODE, bool SCALEC>
__global__ __launch_bounds__(256) void gemm_bt(
    const ushort_t* __restrict__ A, const ushort_t* __restrict__ Bt,
    const float* __restrict__ bias, ushort_t* __restrict__ C,
    int M, int N, int K)
{
    __shared__ ushort_t As[128 * 32];
    __shared__ ushort_t Bs[128 * 32];
    const int t = threadIdx.x;
    const int m0 = blockIdx.y * 128, n0 = blockIdx.x * 128;
    const int wave = t >> 6, lane = t & 63;
    const int l15 = lane & 15, lq = lane >> 4;
    const int wr = wave >> 1, wc = wave & 1;

    f32x4 acc[4][4];
    #pragma unroll
    for (int i = 0; i < 4; ++i)
        #pragma unroll
        for (int j = 0; j < 4; ++j) acc[i][j] = (f32x4){0.f, 0.f, 0.f, 0.f};

    for (int k0 = 0; k0 < K; k0 += 32) {
        __syncthreads();
        #pragma unroll
        for (int i = 0; i < 2; ++i) {      // stage A (2 x 16B per thread)
            int li = i * 256 + t;
            int ml = li >> 2, cp = li & 3;
            int cg = cp ^ ((ml ^ (ml >> 2)) & 3);
            gll16(A + (size_t)(m0 + ml) * K + k0 + cg * 8, &As[li * 8]);
        }
        #pragma unroll
        for (int i = 0; i < 2; ++i) {      // stage B
            int li = i * 256 + t;
            int nl = li >> 2, cp = li & 3;
            int cg = cp ^ ((nl ^ (nl >> 2)) & 3);
            gll16(Bt + (size_t)(n0 + nl) * K + k0 + cg * 8, &Bs[li * 8]);
        }
        __syncthreads();
        bf16x8 af[4], bfr[4];
        #pragma unroll
        for (int i = 0; i < 4; ++i) {
            int r = wr * 64 + i * 16 + l15;
            int pc = lq ^ ((r ^ (r >> 2)) & 3);
            af[i] = *(const bf16x8*)&As[r * 32 + pc * 8];
        }
        #pragma unroll
        for (int j = 0; j < 4; ++j) {
            int r = wc * 64 + j * 16 + l15;
            int pc = lq ^ ((r ^ (r >> 2)) & 3);
            bfr[j] = *(const bf16x8*)&Bs[r * 32 + pc * 8];
        }
        #pragma unroll
        for (int i = 0; i < 4; ++i)
            #pragma unroll
            for (int j = 0; j < 4; ++j)
                acc[i][j] = __builtin_amdgcn_mfma_f32_16x16x32_bf16(af[i], bfr[j], acc[i][j], 0, 0, 0);
    }
    // epilogue: C layout col=lane&15, row=4*quad+e
    if (OMODE == 2) {
        #pragma unroll
        for (int i = 0; i < 4; ++i) {
            int mbase = m0 + wr * 64 + i * 16 + 4 * lq;         // 4-aligned; 200%4==0
            int bb = (int)(((unsigned)mbase * 5243u) >> 20);    // mbase/200
            int ll = mbase - bb * 200;
            #pragma unroll
            for (int j = 0; j < 4; ++j) {
                int n = n0 + wc * 64 + j * 16 + l15;
                float bsv = bias[n];
                ushort4 o4;
                o4.x = f2b(acc[i][j][0] + bsv); o4.y = f2b(acc[i][j][1] + bsv);
                o4.z = f2b(acc[i][j][2] + bsv); o4.w = f2b(acc[i][j][3] + bsv);
                size_t addr = ((size_t)(bb * NH + (n >> 8)) * 256 + (n & 255)) * LSEQ + ll;
                *(ushort4*)&C[addr] = o4;
            }
        }
    } else {
        #pragma unroll
        for (int i = 0; i < 4; ++i) {
            #pragma unroll
            for (int e = 0; e < 4; ++e) {
                int m = m0 + wr * 64 + i * 16 + 4 * lq + e;
                #pragma unroll
                for (int j = 0; j < 4; ++j) {
                    int n = n0 + wc * 64 + j * 16 + l15;
                    float v = acc[i][j][e] + bias[n];
                    if (RELU) v = fmaxf(v, 0.f);
                    if (SCALEC) v *= CSCALE;
                    if (OMODE == 1) {
                        int bb = (int)(((unsigned)m * 5243u) >> 20);
                        int ll = m - bb * 200;
                        size_t addr = ((((size_t)(bb * NH + (n >> 8))) * LSEQ + ll) << 8) + (n & 255);
                        C[addr] = f2b(v);
                    } else {
                        C[(size_t)m * N + n] = f2b(v);
                    }
                }
            }
        }
    }
}

// ================= fused area-attention v15 (2 q-tiles/wave, 256-thr, 2 blk/CU) ======
// v13 structure (in-register P, operand-swapped QK^T, sigma-permuted V, single-buffer
// pooling RMW) with LDS-read amortization: 256 threads / 4 waves per block, each wave
// owns TWO 16-row q-tiles (A = q0+wave*16, B = A+64). Every K A-frag and V B-frag read
// from LDS feeds 2 MFMAs (one per q-tile) -> compute LDS reads per CU halve. Same
// 1024-block grid, same chip-wide staging volume. LDS 64 KB -> 2 independent blocks/CU
// whose barriers drift: one block's staging overlaps the other's MFMA (the overlap v14
// tried to buy with registers and spilled). Regs: qfA/qfB 64 + oaccA/oaccB 128 +
// transients ~245 <= 256 unified budget of (256,2).
__global__ __launch_bounds__(256, 2) void attn_mfma15(
    const ushort_t* __restrict__ Q, const ushort_t* __restrict__ Khm,
    const ushort_t* __restrict__ Vt, ushort_t* __restrict__ O)  // O may alias Q
{
    const int id = blockIdx.x;
    const int xcd = id & 7, slot_ = id >> 3;    // 1024 blocks: 8 xcd x 128 slots
    const int qt = slot_ & 1;
    const int bh = ((slot_ >> 1) << 3) + xcd;   // both q-blocks of bh share an XCD
    const int b = bh >> 3, h = bh & 7;
    const int q0 = qt * 128;
    const int t = threadIdx.x;
    const int wave = t >> 6, lane = t & 63;
    const int l15 = lane & 15, lq = lane >> 4;

    __shared__ ushort_t Ks[64 * 256];      // pooled K [m][d], chunk ^ (m&15), 32 KB
    __shared__ ushort_t Vs[256 * 64];      // pooled V [d][kpos=sigma^-1(m)], chunk ^ (d&7), 32 KB

    const ushort_t* kbh = Khm + (size_t)bh * LSEQ * DH;
    const ushort_t* vtb = Vt + (size_t)bh * DH * LSEQ;   // [d][l]
    const ushort_t* qbh = Q + ((size_t)b * LSEQ) * HD + h * DH;

    // two q-tiles per wave; rows qrA always < 200 (max 191), qrB may be padded
    const int qrA = q0 + wave * 16 + l15;
    const int qrB = qrA + 64;
    bf16x8 qfA[8], qfB[8];
    {
        const ushort_t* qp = qbh + (size_t)qrA * HD + 8 * lq;
        #pragma unroll
        for (int g = 0; g < 8; ++g) qfA[g] = *(const bf16x8*)(qp + 32 * g);
    }
    if (qrB < LSEQ) {
        const ushort_t* qp = qbh + (size_t)qrB * HD + 8 * lq;
        #pragma unroll
        for (int g = 0; g < 8; ++g) qfB[g] = *(const bf16x8*)(qp + 32 * g);
    } else {
        bf16x8 zf = {0,0,0,0,0,0,0,0};
        #pragma unroll
        for (int g = 0; g < 8; ++g) qfB[g] = zf;
    }

    f32x4 oaccA[16], oaccB[16];
    #pragma unroll
    for (int i = 0; i < 16; ++i) {
        oaccA[i] = (f32x4){0.f, 0.f, 0.f, 0.f};
        oaccB[i] = (f32x4){0.f, 0.f, 0.f, 0.f};
    }
    float lA = 0.f, lB = 0.f;   // per-thread partial softmax denominators

    // staging roles for 256 threads
    const int dc = t & 31, mb = t >> 5;      // K: lane->d-chunk, thread->8 m's (mb 0..7)
    const int vd = t;                        // V: thread -> full d row (8 chunks)

    // one MFMA+softmax+PV step over the staged 64-m tile, both q-tiles per wave
    auto step = [&](bool tail) {
        f32x4 sA[4], sB[4];
        __builtin_amdgcn_s_setprio(1);
        #pragma unroll
        for (int ms = 0; ms < 4; ++ms) {
            f32x4 xa = (f32x4){0.f, 0.f, 0.f, 0.f};
            f32x4 xb = (f32x4){0.f, 0.f, 0.f, 0.f};
            const int row = ms * 16 + l15;
            #pragma unroll
            for (int g = 0; g < 8; ++g) {
                const int phys = (lq + 4 * g) ^ l15;
                const bf16x8 kk = *(const bf16x8*)&Ks[row * 256 + phys * 8];
                xa = __builtin_amdgcn_mfma_f32_16x16x32_bf16(kk, qfA[g], xa, 0, 0, 0);
                xb = __builtin_amdgcn_mfma_f32_16x16x32_bf16(kk, qfB[g], xb, 0, 0, 0);
            }
            sA[ms] = xa; sB[ms] = xb;
        }
        __builtin_amdgcn_s_setprio(0);
        // fixed-reference softmax numerator: p = exp2(s); pack to A-frags in registers
        unsigned int wA[8], wB[8];
        #pragma unroll
        for (int ms = 0; ms < 4; ++ms) {
            float pa[4], pb[4];
            #pragma unroll
            for (int e = 0; e < 4; ++e) {
                float va_ = sA[ms][e], vb_ = sB[ms][e];
                if (tail) {  // slot = 8*cls + off, valid iff off <= 7-cls, cls <= 4
                    const int slot = ms * 16 + 4 * lq + e;
                    if (((slot & 7) > 7 - (slot >> 3)) || ((slot >> 3) > 4)) {
                        va_ = -1e30f; vb_ = -1e30f;
                    }
                }
                float ea = __builtin_exp2f(va_);
                float eb = __builtin_exp2f(vb_);
                lA += ea; lB += eb;
                pa[e] = ea; pb[e] = eb;
            }
            asm("v_cvt_pk_bf16_f32 %0, %1, %2" : "=v"(wA[2*ms])   : "v"(pa[0]), "v"(pa[1]));
            asm("v_cvt_pk_bf16_f32 %0, %1, %2" : "=v"(wA[2*ms+1]) : "v"(pa[2]), "v"(pa[3]));
            asm("v_cvt_pk_bf16_f32 %0, %1, %2" : "=v"(wB[2*ms])   : "v"(pb[0]), "v"(pb[1]));
            asm("v_cvt_pk_bf16_f32 %0, %1, %2" : "=v"(wB[2*ms+1]) : "v"(pb[2]), "v"(pb[3]));
        }
        union FR { unsigned int u[4]; bf16x8 v; };
        FR a0, a1, b0, b1;
        a0.u[0] = wA[0]; a0.u[1] = wA[1]; a0.u[2] = wA[2]; a0.u[3] = wA[3];
        a1.u[0] = wA[4]; a1.u[1] = wA[5]; a1.u[2] = wA[6]; a1.u[3] = wA[7];
        b0.u[0] = wB[0]; b0.u[1] = wB[1]; b0.u[2] = wB[2]; b0.u[3] = wB[3];
        b1.u[0] = wB[4]; b1.u[1] = wB[5]; b1.u[2] = wB[6]; b1.u[3] = wB[7];
        const bf16x8 pfA0 = a0.v, pfA1 = a1.v, pfB0 = b0.v, pfB1 = b1.v;
        __builtin_amdgcn_s_setprio(1);
        #pragma unroll
        for (int dt = 0; dt < 16; ++dt) {
            const int d = dt * 16 + l15;
            const bf16x8 v0 = *(const bf16x8*)&Vs[d * 64 + ((lq ^ (d & 7)) * 8)];
            const bf16x8 v1 = *(const bf16x8*)&Vs[d * 64 + (((lq + 4) ^ (d & 7)) * 8)];
            oaccA[dt] = __builtin_amdgcn_mfma_f32_16x16x32_bf16(pfA0, v0, oaccA[dt], 0, 0, 0);
            oaccA[dt] = __builtin_amdgcn_mfma_f32_16x16x32_bf16(pfA1, v1, oaccA[dt], 0, 0, 0);
            oaccB[dt] = __builtin_amdgcn_mfma_f32_16x16x32_bf16(pfB0, v0, oaccB[dt], 0, 0, 0);
            oaccB[dt] = __builtin_amdgcn_mfma_f32_16x16x32_bf16(pfB1, v1, oaccB[dt], 0, 0, 0);
        }
        __builtin_amdgcn_s_setprio(0);
    };

    // ---- 3 full tiles x 5 classes (all 64 m valid; rows <= 195, fully in-bounds) ----
    for (int ti = 0; ti < 3; ++ti) {
        const int st0 = ti * 64;
        #pragma unroll
        for (int cls = 0; cls < 5; ++cls) {
            // prefetch first 4 K chunks (transient; issued before the barrier so their
            // latency hides under the previous step's compute)
            u16x8 kf[4];
            #pragma unroll
            for (int k8 = 0; k8 < 4; ++k8)
                kf[k8] = *(const u16x8*)(kbh + (size_t)(st0 + mb + 8 * k8 + cls) * DH + dc * 8);
            __syncthreads();   // previous step's frag reads done

            // K pooled: running max in Ks (RMW), 8 m's per thread (4 prefetched + 4 direct)
            #pragma unroll
            for (int k8 = 0; k8 < 4; ++k8) {
                int m = mb + 8 * k8;
                ushort_t* kp = &Ks[m * 256 + ((dc ^ (m & 15)) * 8)];
                *(u16x8*)kp = (cls == 0) ? kf[k8] : bmax8(*(const u16x8*)kp, kf[k8]);
            }
            #pragma unroll
            for (int k8 = 4; k8 < 8; ++k8) {
                u16x8 kv = *(const u16x8*)(kbh + (size_t)(st0 + mb + 8 * k8 + cls) * DH + dc * 8);
                int m = mb + 8 * k8;
                ushort_t* kp = &Ks[m * 256 + ((dc ^ (m & 15)) * 8)];
                *(u16x8*)kp = (cls == 0) ? kv : bmax8(*(const u16x8*)kp, kv);
            }
            // V pooled: running sum in Vs (in-place RMW, shifted add), full row per
            // thread, rolling chunk pair. S_c[m] = S_{c-1}[m] + v[st0+m+cls].
            {
                const ushort_t* vrow = vtb + (size_t)vd * LSEQ + st0;
                u16x8 va = *(const u16x8*)vrow;
                #pragma unroll
                for (int cg = 0; cg < 8; ++cg) {
                    u16x8 vb = *(const u16x8*)(vrow + (cg + 1) * 8);  // max elem st0+71 <= 199
                    const int kc = (cg >> 2) * 4 + (cg & 1) * 2;   // sigma chunk (lo half)
                    const int par4 = ((cg >> 1) & 1) * 4;
                    ushort_t* plo = &Vs[vd * 64 + ((kc ^ (vd & 7)) * 8) + par4];
                    ushort_t* phi = &Vs[vd * 64 + (((kc + 1) ^ (vd & 7)) * 8) + par4];
                    union VH { u16x8 v; ushort4 h[2]; };
                    VH nv;
                    if (cls == 0) {
                        nv.v = va;
                    } else {
                        u16x8 sh;
                        #pragma unroll
                        for (int j = 0; j < 8; ++j)
                            sh[j] = (j + cls < 8) ? va[j + cls] : vb[j + cls - 8];
                        VH cur;
                        cur.h[0] = *(const ushort4*)plo;
                        cur.h[1] = *(const ushort4*)phi;
                        nv.v = badd8(cur.v, sh);
                    }
                    *(ushort4*)plo = nv.h[0];
                    *(ushort4*)phi = nv.h[1];
                    va = vb;
                }
            }
            __syncthreads();
            step(false);
        }
    }

    // ---- fused tail step: slot = 8*cls + off, st = 192+off, valid iff off <= 7-cls ----
    {
        __syncthreads();   // previous step's frag reads done
        // K: thread covers slots k8*8+mb (cls=k8, off=mb), incremental max
        {
            u16x8 krun = *(const u16x8*)(kbh + (size_t)(192 + mb) * DH + dc * 8);
            const u16x8 kz = {0,0,0,0,0,0,0,0};
            #pragma unroll
            for (int k8 = 0; k8 < 8; ++k8) {
                const bool vv = (k8 <= 4) && (mb <= 7 - k8);
                if (k8 > 0 && vv)
                    krun = bmax8(krun, *(const u16x8*)(kbh + (size_t)(192 + mb + k8) * DH + dc * 8));
                int slot = k8 * 8 + mb;
                *(u16x8*)&Ks[slot * 256 + ((dc ^ (slot & 15)) * 8)] = vv ? krun : kz;
            }
        }
        // V: thread owns full d-row vd -> all 8 chunks (chunk c == class c; c>4 zero)
        {
            u16x8 v0 = *(const u16x8*)(vtb + (size_t)vd * LSEQ + 192);
            float f[8];
            #pragma unroll
            for (int e = 0; e < 8; ++e) f[e] = b2f(v0[e]);
            #pragma unroll
            for (int c = 0; c < 8; ++c) {
                union VH { u16x8 v; ushort4 h[2]; } ov;
                #pragma unroll
                for (int j = 0; j < 8; ++j) ov.v[j] = 0;
                if (c <= 4) {
                    // direct window sums for class c: ov[j] = sum f[j..j+c], j <= 7-c
                    #pragma unroll
                    for (int j = 0; j < 8; ++j) {
                        if (j <= 7 - c) {
                            float acc = 0.f;
                            #pragma unroll
                            for (int u = 0; u <= 4; ++u)
                                if (u <= c) acc += f[j + u];
                            ov.v[j] = f2b(acc);
                        }
                    }
                }
                const int kc = (c >> 2) * 4 + (c & 1) * 2;
                const int par4 = ((c >> 1) & 1) * 4;
                *(ushort4*)&Vs[vd * 64 + ((kc ^ (vd & 7)) * 8) + par4] = ov.h[0];
                *(ushort4*)&Vs[vd * 64 + (((kc + 1) ^ (vd & 7)) * 8) + par4] = ov.h[1];
            }
        }
        __syncthreads();
        step(true);
    }

    // epilogue: reduce l over the 4 lq groups (2 shuffles each), invert, redistribute
    lA += __shfl_xor(lA, 16); lA += __shfl_xor(lA, 32);
    lB += __shfl_xor(lB, 16); lB += __shfl_xor(lB, 32);
    const float invA = 1.f / lA;
    const float invB = 1.f / lB;

    ushort_t* ob = O + ((size_t)b * LSEQ) * HD + h * DH;
    #pragma unroll
    for (int e = 0; e < 4; ++e) {
        const float la = __shfl(invA, 4 * lq + e);
        const float lb = __shfl(invB, 4 * lq + e);
        const int qA = q0 + wave * 16 + 4 * lq + e;     // always < 200
        const int qB = qA + 64;
        #pragma unroll
        for (int dt = 0; dt < 16; ++dt)
            ob[(size_t)qA * HD + dt * 16 + l15] = f2b(oaccA[dt][e] * la);
        if (qB < LSEQ) {
            #pragma unroll
            for (int dt = 0; dt < 16; ++dt)
                ob[(size_t)qB * HD + dt * 16 + l15] = f2b(oaccB[dt][e] * lb);
        }
    }
}

// ================= residual + LayerNorm: Out = LN(bf16 X + R) =================
template<typename TR, typename TO>
__global__ __launch_bounds__(256) void residual_ln(
    const ushort_t* __restrict__ X, const TR* __restrict__ R, TO* __restrict__ Out)
{
    const int row = blockIdx.x;
    const int t = threadIdx.x;
    const size_t base = (size_t)row * HID;
    float v = b2f(X[base + t]) + to_f32(R[base + t]);
    float s = v, q = v * v;
    #pragma unroll
    for (int o = 32; o > 0; o >>= 1) {
        s += __shfl_xor(s, o, 64);
        q += __shfl_xor(q, o, 64);
    }
    __shared__ float ss[4], sq[4];
    const int wave = t >> 6, lane = t & 63;
    if (lane == 0) { ss[wave] = s; sq[wave] = q; }
    __syncthreads();
    s = ss[0] + ss[1] + ss[2] + ss[3];
    q = sq[0] + sq[1] + sq[2] + sq[3];
    float mean = s * (1.f / HID);
    float var  = q * (1.f / HID) - mean * mean;
    store_val(&Out[base + t], (v - mean) * rsqrtf(var + EPS));
}

// ================= converts =================
__global__ __launch_bounds__(256) void cvt_f32_bf16(const float* __restrict__ in,
                                                    ushort_t* __restrict__ out) {
    const int i = (blockIdx.x * 256 + threadIdx.x) * 4;
    float4 v = *(const float4*)(in + i);
    ushort4 o;
    o.x = f2b(v.x); o.y = f2b(v.y); o.z = f2b(v.z); o.w = f2b(v.w);
    *(ushort4*)(out + i) = o;
}

// W[K,N] f32 -> Wt[N,K] bf16
__global__ __launch_bounds__(256) void wtrans(const float* __restrict__ W,
                                              ushort_t* __restrict__ Wt, int K, int N) {
    __shared__ float tile[32][33];
    const int t = threadIdx.x;
    const int tx = t & 31, ty = t >> 5;
    const int n0 = blockIdx.x * 32, k0 = blockIdx.y * 32;
    #pragma unroll
    for (int s = 0; s < 4; ++s)
        tile[ty + 8 * s][tx] = W[(size_t)(k0 + ty + 8 * s) * N + n0 + tx];
    __syncthreads();
    #pragma unroll
    for (int s = 0; s < 4; ++s)
        Wt[(size_t)(n0 + ty + 8 * s) * K + k0 + tx] = f2b(tile[tx][ty + 8 * s]);
}

// ================= launch =================
extern "C" void kernel_launch(void* const* d_in, const int* in_sizes, int n_in,
                              void* d_out, int out_size, void* d_ws, size_t ws_size,
                              hipStream_t stream) {
    const float* hidden = (const float*)d_in[1];
    const float* Wq = (const float*)d_in[2];  const float* bq = (const float*)d_in[3];
    const float* Wk = (const float*)d_in[4];  const float* bk = (const float*)d_in[5];
    const float* Wv = (const float*)d_in[6];  const float* bv = (const float*)d_in[7];
    const float* Wo = (const float*)d_in[8];  const float* bo = (const float*)d_in[9];
    const float* W1 = (const float*)d_in[10]; const float* b1 = (const float*)d_in[11];
    const float* W2 = (const float*)d_in[12]; const float* b2 = (const float*)d_in[13];
    float* out = (float*)d_out;

    constexpr size_t SZ_BF   = (size_t)MROWS * HD * 2;      // 52,428,800
    constexpr size_t SZ_HBF  = (size_t)MROWS * HID * 2;     // 6,553,600
    constexpr size_t SZ_WQKV = (size_t)HID * HD * 2;        // 1,048,576
    constexpr size_t SZ_W12  = (size_t)HID * 4 * HID * 2;   // 524,288
    char* ws = (char*)d_ws;
    size_t off = 0;
    ushort_t* kb   = (ushort_t*)(ws + off); off += SZ_BF;   // K head-major [b,h][l][d]
    ushort_t* vt   = (ushort_t*)(ws + off); off += SZ_BF;   // V transposed  [b,h][d][l]
    ushort_t* qo   = (ushort_t*)(ws + off); off += SZ_BF;   // q / attn-out / ffn1
    ushort_t* hb   = (ushort_t*)(ws + off); off += SZ_HBF;  // hidden bf16
    ushort_t* at1  = (ushort_t*)(ws + off); off += SZ_HBF;
    ushort_t* at2  = (ushort_t*)(ws + off); off += SZ_HBF;
    ushort_t* proj = (ushort_t*)(ws + off); off += SZ_HBF;
    ushort_t* WtQ  = (ushort_t*)(ws + off); off += SZ_WQKV;
    ushort_t* WtK  = (ushort_t*)(ws + off); off += SZ_WQKV;
    ushort_t* WtV  = (ushort_t*)(ws + off); off += SZ_WQKV;
    ushort_t* WtO  = (ushort_t*)(ws + off); off += SZ_WQKV;
    ushort_t* Wt1  = (ushort_t*)(ws + off); off += SZ_W12;
    ushort_t* Wt2  = (ushort_t*)(ws + off); off += SZ_W12;
    if (ws_size < off) return;  // total == 188,743,680 B (same as passing R3/R5-R11)
    ushort_t* ffn1 = qo;        // alias: qo free after out-proj2

    dim3 blk(256);
    cvt_f32_bf16<<<MROWS * HID / 1024, blk, 0, stream>>>(hidden, hb);
    wtrans<<<dim3(HD / 32, HID / 32), blk, 0, stream>>>(Wq, WtQ, HID, HD);
    wtrans<<<dim3(HD / 32, HID / 32), blk, 0, stream>>>(Wk, WtK, HID, HD);
    wtrans<<<dim3(HD / 32, HID / 32), blk, 0, stream>>>(Wv, WtV, HID, HD);
    wtrans<<<dim3(HID / 32, HD / 32), blk, 0, stream>>>(Wo, WtO, HD, HID);
    wtrans<<<dim3(4 * HID / 32, HID / 32), blk, 0, stream>>>(W1, Wt1, HID, 4 * HID);
    wtrans<<<dim3(HID / 32, 4 * HID / 32), blk, 0, stream>>>(W2, Wt2, 4 * HID, HID);

    const dim3 gProj(HD / 128, MROWS / 128);
    const dim3 gOut(HID / 128, MROWS / 128);
    const dim3 gF1(4 * HID / 128, MROWS / 128);

    // K head-major; V transposed head-major (shared by both MHAs)
    gemm_bt<false, 1, false><<<gProj, blk, 0, stream>>>(hb, WtK, bk, kb, MROWS, HD, HID);
    gemm_bt<false, 2, false><<<gProj, blk, 0, stream>>>(hb, WtV, bv, vt, MROWS, HD, HID);

    // MHA1 (Q pre-scaled by CSCALE)
    gemm_bt<false, 0, true><<<gProj, blk, 0, stream>>>(hb, WtQ, bq, qo, MROWS, HD, HID);
    attn_mfma15<<<2 * BATCH * NH, 256, 0, stream>>>(qo, kb, vt, qo);
    gemm_bt<false, 0, false><<<gOut, blk, 0, stream>>>(qo, WtO, bo, proj, MROWS, HID, HD);
    residual_ln<float, ushort_t><<<MROWS, blk, 0, stream>>>(proj, hidden, at1);

    // MHA2 (q from attn1; pooled K/V rebuilt from same kb/vt)
    gemm_bt<false, 0, true><<<gProj, blk, 0, stream>>>(at1, WtQ, bq, qo, MROWS, HD, HID);
    attn_mfma15<<<2 * BATCH * NH, 256, 0, stream>>>(qo, kb, vt, qo);
    gemm_bt<false, 0, false><<<gOut, blk, 0, stream>>>(qo, WtO, bo, proj, MROWS, HID, HD);
    residual_ln<ushort_t, ushort_t><<<MROWS, blk, 0, stream>>>(proj, at1, at2);

    // FFN
    gemm_bt<true, 0, false><<<gF1, blk, 0, stream>>>(at2, Wt1, b1, ffn1, MROWS, 4 * HID, HID);
    gemm_bt<false, 0, false><<<gOut, blk, 0, stream>>>(ffn1, Wt2, b2, proj, MROWS, HID, 4 * HID);
    residual_ln<ushort_t, float><<<MROWS, blk, 0, stream>>>(proj, at2, out);
}

// Round 5
// 902.271 us; speedup vs baseline: 1.9019x; 1.8529x over previous
//
#include <hip/hip_runtime.h>
#include <hip/hip_bf16.h>
#include <cstdint>
#include <cstddef>

// Problem constants
#define BATCH 64
#define LSEQ 200
#define HID 256
#define NH 8
#define DH 256            // per-head dim = HID
#define HD (NH*DH)        // 2048
#define MROWS (BATCH*LSEQ)   // 12800
#define EPS 1e-5f
#define CSCALE 0.09014195f   // (1/sqrt(256)) * log2(e), folded into Q projection

typedef unsigned short ushort_t;
typedef __attribute__((ext_vector_type(8))) short bf16x8;         // MFMA A/B frag (4 VGPR)
typedef __attribute__((ext_vector_type(8))) unsigned short u16x8; // 16B of bf16
typedef __attribute__((ext_vector_type(4))) float f32x4;          // MFMA C/D frag

__device__ __forceinline__ float b2f(ushort_t u) {
    union { unsigned int i; float f; } c; c.i = ((unsigned int)u) << 16; return c.f;
}
__device__ __forceinline__ ushort_t f2b(float f) {
    __hip_bfloat16 h = __float2bfloat16(f);
    union { __hip_bfloat16 h; ushort_t u; } c; c.h = h; return c.u;
}
__device__ __forceinline__ float to_f32(float x) { return x; }
__device__ __forceinline__ float to_f32(ushort_t x) { return b2f(x); }
__device__ __forceinline__ void store_val(float* p, float v) { *p = v; }
__device__ __forceinline__ void store_val(ushort_t* p, float v) { *p = f2b(v); }

// packed bf16 max / add on 8 elements
__device__ __forceinline__ u16x8 bmax8(u16x8 a, u16x8 b) {
    union U { u16x8 v; __hip_bfloat162 h[4]; };
    U ua, ub, r; ua.v = a; ub.v = b;
    #pragma unroll
    for (int i = 0; i < 4; ++i) r.h[i] = __hmax2(ua.h[i], ub.h[i]);
    return r.v;
}
__device__ __forceinline__ u16x8 badd8(u16x8 a, u16x8 b) {
    union U { u16x8 v; __hip_bfloat162 h[4]; };
    U ua, ub, r; ua.v = a; ub.v = b;
    #pragma unroll
    for (int i = 0; i < 4; ++i) r.h[i] = __hadd2(ua.h[i], ub.h[i]);
    return r.v;
}

// async global->LDS, 16 bytes per lane (LDS dest = wave-uniform base + lane*16)
__device__ __forceinline__ void gll16(const void* g, void* l) {
    __builtin_amdgcn_global_load_lds(
        (const __attribute__((address_space(1))) unsigned int*)g,
        (__attribute__((address_space(3))) unsigned int*)l, 16, 0, 0);
}

// ================= bf16 MFMA GEMM:  C[M,N] = A[M,K] @ Bt[N,K]^T + bias =================
// 128x128 tile, BK=32, 4 waves (2x2 of 64x64), global_load_lds staging, XOR-swizzled LDS.
// OMODE: 0 = row-major [m][n]; 1 = head-major [b][h][l][d]; 2 = transposed head-major
// [b][h][d][l] (row length LSEQ=200, 8B packed stores). Modes 1/2 require N==2048.
// SCALEC: multiply (acc+bias) by CSCALE (folds softmax scale*log2e into Q projection).
template<bool RELU, int OMODE, bool SCALEC>
__global__ __launch_bounds__(256) void gemm_bt(
    const ushort_t* __restrict__ A, const ushort_t* __restrict__ Bt,
    const float* __restrict__ bias, ushort_t* __restrict__ C,
    int M, int N, int K)
{
    __shared__ ushort_t As[128 * 32];
    __shared__ ushort_t Bs[128 * 32];
    const int t = threadIdx.x;
    const int m0 = blockIdx.y * 128, n0 = blockIdx.x * 128;
    const int wave = t >> 6, lane = t & 63;
    const int l15 = lane & 15, lq = lane >> 4;
    const int wr = wave >> 1, wc = wave & 1;

    f32x4 acc[4][4];
    #pragma unroll
    for (int i = 0; i < 4; ++i)
        #pragma unroll
        for (int j = 0; j < 4; ++j) acc[i][j] = (f32x4){0.f, 0.f, 0.f, 0.f};

    for (int k0 = 0; k0 < K; k0 += 32) {
        __syncthreads();
        #pragma unroll
        for (int i = 0; i < 2; ++i) {      // stage A (2 x 16B per thread)
            int li = i * 256 + t;
            int ml = li >> 2, cp = li & 3;
            int cg = cp ^ ((ml ^ (ml >> 2)) & 3);
            gll16(A + (size_t)(m0 + ml) * K + k0 + cg * 8, &As[li * 8]);
        }
        #pragma unroll
        for (int i = 0; i < 2; ++i) {      // stage B
            int li = i * 256 + t;
            int nl = li >> 2, cp = li & 3;
            int cg = cp ^ ((nl ^ (nl >> 2)) & 3);
            gll16(Bt + (size_t)(n0 + nl) * K + k0 + cg * 8, &Bs[li * 8]);
        }
        __syncthreads();
        bf16x8 af[4], bfr[4];
        #pragma unroll
        for (int i = 0; i < 4; ++i) {
            int r = wr * 64 + i * 16 + l15;
            int pc = lq ^ ((r ^ (r >> 2)) & 3);
            af[i] = *(const bf16x8*)&As[r * 32 + pc * 8];
        }
        #pragma unroll
        for (int j = 0; j < 4; ++j) {
            int r = wc * 64 + j * 16 + l15;
            int pc = lq ^ ((r ^ (r >> 2)) & 3);
            bfr[j] = *(const bf16x8*)&Bs[r * 32 + pc * 8];
        }
        #pragma unroll
        for (int i = 0; i < 4; ++i)
            #pragma unroll
            for (int j = 0; j < 4; ++j)
                acc[i][j] = __builtin_amdgcn_mfma_f32_16x16x32_bf16(af[i], bfr[j], acc[i][j], 0, 0, 0);
    }
    // epilogue: C layout col=lane&15, row=4*quad+e
    if (OMODE == 2) {
        #pragma unroll
        for (int i = 0; i < 4; ++i) {
            int mbase = m0 + wr * 64 + i * 16 + 4 * lq;         // 4-aligned; 200%4==0
            int bb = (int)(((unsigned)mbase * 5243u) >> 20);    // mbase/200
            int ll = mbase - bb * 200;
            #pragma unroll
            for (int j = 0; j < 4; ++j) {
                int n = n0 + wc * 64 + j * 16 + l15;
                float bsv = bias[n];
                ushort4 o4;
                o4.x = f2b(acc[i][j][0] + bsv); o4.y = f2b(acc[i][j][1] + bsv);
                o4.z = f2b(acc[i][j][2] + bsv); o4.w = f2b(acc[i][j][3] + bsv);
                size_t addr = ((size_t)(bb * NH + (n >> 8)) * 256 + (n & 255)) * LSEQ + ll;
                *(ushort4*)&C[addr] = o4;
            }
        }
    } else {
        #pragma unroll
        for (int i = 0; i < 4; ++i) {
            #pragma unroll
            for (int e = 0; e < 4; ++e) {
                int m = m0 + wr * 64 + i * 16 + 4 * lq + e;
                #pragma unroll
                for (int j = 0; j < 4; ++j) {
                    int n = n0 + wc * 64 + j * 16 + l15;
                    float v = acc[i][j][e] + bias[n];
                    if (RELU) v = fmaxf(v, 0.f);
                    if (SCALEC) v *= CSCALE;
                    if (OMODE == 1) {
                        int bb = (int)(((unsigned)m * 5243u) >> 20);
                        int ll = m - bb * 200;
                        size_t addr = ((((size_t)(bb * NH + (n >> 8))) * LSEQ + ll) << 8) + (n & 255);
                        C[addr] = f2b(v);
                    } else {
                        C[(size_t)m * N + n] = f2b(v);
                    }
                }
            }
        }
    }
}

// ================= fused area-attention v16 (raw-V PV via P aggregation) =============
// v13 base (in-register P, operand-swapped QK^T, sigma-permuted V, 64 KB LDS,
// __launch_bounds__(512,2)) with the sum-pool PV re-associated onto RAW V:
//   O = sum_{c,s} P_{c,s} * sum_u V[s+u]  =  sum_j V[j] * Pagg[j],
//   Pagg[j] = sum_c sum_{u<=c} P_c[j-u]   (backward window sums, in-register).
// Per 64-slot tile: 5 QK class steps accumulate Pagg (shift1 = lane-rotate + 4 shfl
// for lq boundary), then ONE PV over raw V (staged once at class 0, no pooling RMW).
// Removes 128/320 MFMAs per tile, 4/5 V LDS-read passes, all V pool staging.
// Cross-tile spill (<=4 slots): carry[4] regs, shuffled into next tile's Pagg[0][*]
// (lq==0 lanes). Tile-2 carry is injected into the v13 tail step via the unused
// class-5 slots (40..43), with raw V[192..195] staged in the free chunk-5 of Vs.
__global__ __launch_bounds__(512, 2) void attn_mfma16(
    const ushort_t* __restrict__ Q, const ushort_t* __restrict__ Khm,
    const ushort_t* __restrict__ Vt, ushort_t* __restrict__ O)  // O may alias Q
{
    const int id = blockIdx.x;
    const int xcd = id & 7, slot_ = id >> 3;    // 1024 blocks: 8 xcd x 128 slots
    const int qt = slot_ & 1;
    const int bh = ((slot_ >> 1) << 3) + xcd;   // both q-blocks of bh share an XCD
    const int b = bh >> 3, h = bh & 7;
    const int q0 = qt * 128;
    const int t = threadIdx.x;
    const int wave = t >> 6, lane = t & 63;
    const int l15 = lane & 15, lq = lane >> 4;

    __shared__ ushort_t Ks[64 * 256];      // pooled K [m][d], chunk ^ (m&15), 32 KB
    __shared__ ushort_t Vs[256 * 64];      // V [d][kpos=sigma^-1(m)], chunk ^ (d&7), 32 KB

    const ushort_t* kbh = Khm + (size_t)bh * LSEQ * DH;
    const ushort_t* vtb = Vt + (size_t)bh * DH * LSEQ;   // [d][l]
    const ushort_t* qbh = Q + ((size_t)b * LSEQ) * HD + h * DH;
    const int qrow = q0 + wave * 16 + l15;

    // Q fragments (row=lane&15, k=8*quad+j); pre-scaled by CSCALE in GEMM.
    bf16x8 qf[8];
    if (qrow < LSEQ) {
        const ushort_t* qp = qbh + (size_t)qrow * HD + 8 * lq;
        #pragma unroll
        for (int g = 0; g < 8; ++g) qf[g] = *(const bf16x8*)(qp + 32 * g);
    } else {
        bf16x8 zf = {0,0,0,0,0,0,0,0};
        #pragma unroll
        for (int g = 0; g < 8; ++g) qf[g] = zf;
    }

    f32x4 oacc[16];
    #pragma unroll
    for (int i = 0; i < 16; ++i) oacc[i] = (f32x4){0.f, 0.f, 0.f, 0.f};
    float l_part = 0.f;
    float carry[4];                        // spill of Pagg into next tile's slots 0..3
    #pragma unroll
    for (int e = 0; e < 4; ++e) carry[e] = 0.f;

    // staging roles for 512 threads
    const int dc = t & 31, mb = t >> 5;      // K: lane->d-chunk, thread->4 m's (mb 0..15)
    const int vd = t >> 1, vh = t & 1;       // V: thread -> d row, half (4 chunks each)

    // shift slot axis down by 1 (T'[slot] = T[slot-1], 0 fill at slot 0)
    auto shift1 = [&](float T[4][4]) {
        float up0 = __shfl(T[0][3], (lane - 16) & 63);
        float up1 = __shfl(T[1][3], (lane - 16) & 63);
        float up2 = __shfl(T[2][3], (lane - 16) & 63);
        float up3 = __shfl(T[3][3], (lane - 16) & 63);
        #pragma unroll
        for (int ms = 0; ms < 4; ++ms) {
            T[ms][3] = T[ms][2]; T[ms][2] = T[ms][1]; T[ms][1] = T[ms][0];
        }
        T[3][0] = (lq > 0) ? up3 : up2;
        T[2][0] = (lq > 0) ? up2 : up1;
        T[1][0] = (lq > 0) ? up1 : up0;
        T[0][0] = (lq > 0) ? up0 : 0.f;
    };

    // PV over the staged V tile with A-frags from float P[4][4]
    auto pv32 = [&](const float P[4][4]) {
        unsigned int w[8];
        #pragma unroll
        for (int ms = 0; ms < 4; ++ms) {
            asm("v_cvt_pk_bf16_f32 %0, %1, %2" : "=v"(w[2*ms])   : "v"(P[ms][0]), "v"(P[ms][1]));
            asm("v_cvt_pk_bf16_f32 %0, %1, %2" : "=v"(w[2*ms+1]) : "v"(P[ms][2]), "v"(P[ms][3]));
        }
        union FR { unsigned int u[4]; bf16x8 v; };
        FR f0, f1;
        f0.u[0] = w[0]; f0.u[1] = w[1]; f0.u[2] = w[2]; f0.u[3] = w[3];
        f1.u[0] = w[4]; f1.u[1] = w[5]; f1.u[2] = w[6]; f1.u[3] = w[7];
        const bf16x8 pf0 = f0.v, pf1 = f1.v;
        __builtin_amdgcn_s_setprio(1);
        #pragma unroll
        for (int dt = 0; dt < 16; ++dt) {
            const int d = dt * 16 + l15;
            const int p0 = lq ^ (d & 7);
            const int p1 = (lq + 4) ^ (d & 7);
            oacc[dt] = __builtin_amdgcn_mfma_f32_16x16x32_bf16(
                           pf0, *(const bf16x8*)&Vs[d * 64 + p0 * 8], oacc[dt], 0, 0, 0);
            oacc[dt] = __builtin_amdgcn_mfma_f32_16x16x32_bf16(
                           pf1, *(const bf16x8*)&Vs[d * 64 + p1 * 8], oacc[dt], 0, 0, 0);
        }
        __builtin_amdgcn_s_setprio(0);
    };

    // ---- 3 full tiles x 5 QK classes + 1 PV each ----
    for (int ti = 0; ti < 3; ++ti) {
        const int st0 = ti * 64;
        // carry-in: prev tile's spill -> this tile's slots 0..3 (lq==0 lanes)
        float Pagg[4][4];
        {
            float pin0 = __shfl(carry[0], (lane + 48) & 63);
            float pin1 = __shfl(carry[1], (lane + 48) & 63);
            float pin2 = __shfl(carry[2], (lane + 48) & 63);
            float pin3 = __shfl(carry[3], (lane + 48) & 63);
            #pragma unroll
            for (int ms = 0; ms < 4; ++ms)
                #pragma unroll
                for (int e = 0; e < 4; ++e) Pagg[ms][e] = 0.f;
            if (lq == 0) {
                Pagg[0][0] = pin0; Pagg[0][1] = pin1; Pagg[0][2] = pin2; Pagg[0][3] = pin3;
            }
            #pragma unroll
            for (int e = 0; e < 4; ++e) carry[e] = 0.f;
        }
        #pragma unroll
        for (int cls = 0; cls < 5; ++cls) {
            // prefetch raw K rows (+cls); raw V rows at cls==0 (once per tile)
            u16x8 kf[4];
            #pragma unroll
            for (int k4 = 0; k4 < 4; ++k4)
                kf[k4] = *(const u16x8*)(kbh + (size_t)(st0 + mb + 16 * k4 + cls) * DH + dc * 8);
            u16x8 vc[4];
            if (cls == 0) {
                const ushort_t* vrow = vtb + (size_t)vd * LSEQ + st0 + vh * 32;
                #pragma unroll
                for (int c2 = 0; c2 < 4; ++c2) vc[c2] = *(const u16x8*)(vrow + c2 * 8);
            }
            __syncthreads();   // previous step's frag reads done

            // K pooled: running max in Ks (in-place RMW), 4 chunks/thread
            #pragma unroll
            for (int k4 = 0; k4 < 4; ++k4) {
                int m = mb + 16 * k4;
                ushort_t* kp = &Ks[m * 256 + ((dc ^ (m & 15)) * 8)];
                *(u16x8*)kp = (cls == 0) ? kf[k4] : bmax8(*(const u16x8*)kp, kf[k4]);
            }
            // raw V staged once per tile (sigma-permuted split stores)
            if (cls == 0) {
                #pragma unroll
                for (int cl = 0; cl < 4; ++cl) {
                    const int cg = vh * 4 + cl;                    // natural chunk 0..7
                    const int kc = (cg >> 2) * 4 + (cg & 1) * 2;   // sigma chunk (lo half)
                    const int par4 = ((cg >> 1) & 1) * 4;
                    union VH { u16x8 v; ushort4 hh[2]; } nv;
                    nv.v = vc[cl];
                    *(ushort4*)&Vs[vd * 64 + ((kc ^ (vd & 7)) * 8) + par4] = nv.hh[0];
                    *(ushort4*)&Vs[vd * 64 + (((kc + 1) ^ (vd & 7)) * 8) + par4] = nv.hh[1];
                }
            }
            __syncthreads();

            // QK^T for this class (swapped operands): sacc[ms][e] = S^T[slot][q=l15]
            f32x4 sacc[4];
            __builtin_amdgcn_s_setprio(1);
            #pragma unroll
            for (int ms = 0; ms < 4; ++ms) {
                f32x4 s = (f32x4){0.f, 0.f, 0.f, 0.f};
                const int row = ms * 16 + l15;
                #pragma unroll
                for (int g = 0; g < 8; ++g) {
                    const int phys = (lq + 4 * g) ^ l15;
                    s = __builtin_amdgcn_mfma_f32_16x16x32_bf16(
                            *(const bf16x8*)&Ks[row * 256 + phys * 8], qf[g], s, 0, 0, 0);
                }
                sacc[ms] = s;
            }
            __builtin_amdgcn_s_setprio(0);

            // P_c = exp2(s); accumulate Pagg += sum_{u=0..cls} shift_u(P_c)
            float Pc[4][4];
            #pragma unroll
            for (int ms = 0; ms < 4; ++ms)
                #pragma unroll
                for (int e = 0; e < 4; ++e) {
                    float pe = __builtin_exp2f(sacc[ms][e]);
                    l_part += pe;
                    Pc[ms][e] = pe;
                    Pagg[ms][e] += pe;
                }
            if (cls >= 1) {
                float T[4][4];
                #pragma unroll
                for (int ms = 0; ms < 4; ++ms)
                    #pragma unroll
                    for (int e = 0; e < 4; ++e) T[ms][e] = Pc[ms][e];
                #pragma unroll
                for (int u = 1; u <= 4; ++u) {
                    if (u <= cls) {
                        shift1(T);
                        #pragma unroll
                        for (int ms = 0; ms < 4; ++ms)
                            #pragma unroll
                            for (int e = 0; e < 4; ++e) Pagg[ms][e] += T[ms][e];
                    }
                }
            }
            // carry-out: spill to next tile's slot i (meaningful in lq==3 lanes;
            // carry[i] += sum over e >= 4+i-cls of Pc[ms=3][e], i.e. slots 60..63)
            #pragma unroll
            for (int i = 0; i < 4; ++i)
                #pragma unroll
                for (int e = 0; e < 4; ++e)
                    if (cls >= 4 + i - e) carry[i] += Pc[3][e];

            if (cls == 4) pv32(Pagg);   // one PV over raw V for the whole tile
        }
    }

    // ---- tail step (v13's pooled-V tail) + tile-2 carry injection ----
    {
        __syncthreads();   // previous step's frag reads (incl. PV) done
        // K: threads with mb<8 cover slots k8*8+mb (cls=k8, off=mb), incremental max
        if (mb < 8) {
            u16x8 krun = *(const u16x8*)(kbh + (size_t)(192 + mb) * DH + dc * 8);
            const u16x8 kz = {0,0,0,0,0,0,0,0};
            #pragma unroll
            for (int k8 = 0; k8 < 8; ++k8) {
                const bool v = (k8 <= 4) && (mb <= 7 - k8);
                if (k8 > 0 && v)
                    krun = bmax8(krun, *(const u16x8*)(kbh + (size_t)(192 + mb + k8) * DH + dc * 8));
                int slot = k8 * 8 + mb;
                *(u16x8*)&Ks[slot * 256 + ((dc ^ (slot & 15)) * 8)] = v ? krun : kz;
            }
        }
        // V: thread owns d=vd, half vh -> chunks vh*4..vh*4+3; window sums for c<=4,
        // chunk 5 = raw V[192..195] (carry target), chunks 6,7 zero.
        {
            u16x8 v0 = *(const u16x8*)(vtb + (size_t)vd * LSEQ + 192);
            float f[8];
            #pragma unroll
            for (int e = 0; e < 8; ++e) f[e] = b2f(v0[e]);
            #pragma unroll
            for (int cl = 0; cl < 4; ++cl) {
                const int c = vh * 4 + cl;     // chunk c == class c (slots 8c..8c+7)
                union VH { u16x8 v; ushort4 hh[2]; } ov;
                #pragma unroll
                for (int j = 0; j < 8; ++j) ov.v[j] = 0;
                if (c <= 4) {
                    // direct window sums for class c: ov[j] = sum f[j..j+c], j <= 7-c
                    #pragma unroll
                    for (int j = 0; j < 8; ++j) {
                        if (j <= 7 - c) {
                            float acc = 0.f;
                            #pragma unroll
                            for (int u = 0; u <= 4; ++u)
                                if (u <= c) acc += f[j + u];
                            ov.v[j] = f2b(acc);
                        }
                    }
                } else if (c == 5) {
                    #pragma unroll
                    for (int j = 0; j < 4; ++j) ov.v[j] = v0[j];   // raw V[192+j]
                }
                const int kc = (c >> 2) * 4 + (c & 1) * 2;
                const int par4 = ((c >> 1) & 1) * 4;
                *(ushort4*)&Vs[vd * 64 + ((kc ^ (vd & 7)) * 8) + par4] = ov.hh[0];
                *(ushort4*)&Vs[vd * 64 + (((kc + 1) ^ (vd & 7)) * 8) + par4] = ov.hh[1];
            }
        }
        __syncthreads();

        // QK^T tail
        f32x4 sacc[4];
        __builtin_amdgcn_s_setprio(1);
        #pragma unroll
        for (int ms = 0; ms < 4; ++ms) {
            f32x4 s = (f32x4){0.f, 0.f, 0.f, 0.f};
            const int row = ms * 16 + l15;
            #pragma unroll
            for (int g = 0; g < 8; ++g) {
                const int phys = (lq + 4 * g) ^ l15;
                s = __builtin_amdgcn_mfma_f32_16x16x32_bf16(
                        *(const bf16x8*)&Ks[row * 256 + phys * 8], qf[g], s, 0, 0, 0);
            }
            sacc[ms] = s;
        }
        __builtin_amdgcn_s_setprio(0);

        // softmax + carry injection into slots 40..43 (ms==2, lq==2)
        float pullc[4];
        #pragma unroll
        for (int e = 0; e < 4; ++e) pullc[e] = __shfl(carry[e], (lane + 16) & 63);
        float Pt[4][4];
        #pragma unroll
        for (int ms = 0; ms < 4; ++ms)
            #pragma unroll
            for (int e = 0; e < 4; ++e) {
                const int slot = ms * 16 + 4 * lq + e;
                const bool inval = ((slot & 7) > 7 - (slot >> 3)) || ((slot >> 3) > 4);
                float pe = __builtin_exp2f(inval ? -1e30f : sacc[ms][e]);
                l_part += pe;          // carry slots are invalid -> pe==0 here
                float pfrag = pe;
                if (ms == 2 && lq == 2) pfrag = pullc[e];
                Pt[ms][e] = pfrag;
            }
        pv32(Pt);
    }

    // epilogue: reduce l over the 4 lq groups (2 shuffles), invert, redistribute
    l_part += __shfl_xor(l_part, 16);
    l_part += __shfl_xor(l_part, 32);
    const float inv = 1.f / l_part;

    ushort_t* ob = O + ((size_t)b * LSEQ) * HD + h * DH;
    #pragma unroll
    for (int e = 0; e < 4; ++e) {
        const int q = q0 + wave * 16 + 4 * lq + e;
        const float linv = __shfl(inv, 4 * lq + e);
        if (q < LSEQ) {
            #pragma unroll
            for (int dt = 0; dt < 16; ++dt)
                ob[(size_t)q * HD + dt * 16 + l15] = f2b(oacc[dt][e] * linv);
        }
    }
}

// ================= residual + LayerNorm: Out = LN(bf16 X + R) =================
template<typename TR, typename TO>
__global__ __launch_bounds__(256) void residual_ln(
    const ushort_t* __restrict__ X, const TR* __restrict__ R, TO* __restrict__ Out)
{
    const int row = blockIdx.x;
    const int t = threadIdx.x;
    const size_t base = (size_t)row * HID;
    float v = b2f(X[base + t]) + to_f32(R[base + t]);
    float s = v, q = v * v;
    #pragma unroll
    for (int o = 32; o > 0; o >>= 1) {
        s += __shfl_xor(s, o, 64);
        q += __shfl_xor(q, o, 64);
    }
    __shared__ float ss[4], sq[4];
    const int wave = t >> 6, lane = t & 63;
    if (lane == 0) { ss[wave] = s; sq[wave] = q; }
    __syncthreads();
    s = ss[0] + ss[1] + ss[2] + ss[3];
    q = sq[0] + sq[1] + sq[2] + sq[3];
    float mean = s * (1.f / HID);
    float var  = q * (1.f / HID) - mean * mean;
    store_val(&Out[base + t], (v - mean) * rsqrtf(var + EPS));
}

// ================= converts =================
__global__ __launch_bounds__(256) void cvt_f32_bf16(const float* __restrict__ in,
                                                    ushort_t* __restrict__ out) {
    const int i = (blockIdx.x * 256 + threadIdx.x) * 4;
    float4 v = *(const float4*)(in + i);
    ushort4 o;
    o.x = f2b(v.x); o.y = f2b(v.y); o.z = f2b(v.z); o.w = f2b(v.w);
    *(ushort4*)(out + i) = o;
}

// W[K,N] f32 -> Wt[N,K] bf16
__global__ __launch_bounds__(256) void wtrans(const float* __restrict__ W,
                                              ushort_t* __restrict__ Wt, int K, int N) {
    __shared__ float tile[32][33];
    const int t = threadIdx.x;
    const int tx = t & 31, ty = t >> 5;
    const int n0 = blockIdx.x * 32, k0 = blockIdx.y * 32;
    #pragma unroll
    for (int s = 0; s < 4; ++s)
        tile[ty + 8 * s][tx] = W[(size_t)(k0 + ty + 8 * s) * N + n0 + tx];
    __syncthreads();
    #pragma unroll
    for (int s = 0; s < 4; ++s)
        Wt[(size_t)(n0 + ty + 8 * s) * K + k0 + tx] = f2b(tile[tx][ty + 8 * s]);
}

// ================= launch =================
extern "C" void kernel_launch(void* const* d_in, const int* in_sizes, int n_in,
                              void* d_out, int out_size, void* d_ws, size_t ws_size,
                              hipStream_t stream) {
    const float* hidden = (const float*)d_in[1];
    const float* Wq = (const float*)d_in[2];  const float* bq = (const float*)d_in[3];
    const float* Wk = (const float*)d_in[4];  const float* bk = (const float*)d_in[5];
    const float* Wv = (const float*)d_in[6];  const float* bv = (const float*)d_in[7];
    const float* Wo = (const float*)d_in[8];  const float* bo = (const float*)d_in[9];
    const float* W1 = (const float*)d_in[10]; const float* b1 = (const float*)d_in[11];
    const float* W2 = (const float*)d_in[12]; const float* b2 = (const float*)d_in[13];
    float* out = (float*)d_out;

    constexpr size_t SZ_BF   = (size_t)MROWS * HD * 2;      // 52,428,800
    constexpr size_t SZ_HBF  = (size_t)MROWS * HID * 2;     // 6,553,600
    constexpr size_t SZ_WQKV = (size_t)HID * HD * 2;        // 1,048,576
    constexpr size_t SZ_W12  = (size_t)HID * 4 * HID * 2;   // 524,288
    char* ws = (char*)d_ws;
    size_t off = 0;
    ushort_t* kb   = (ushort_t*)(ws + off); off += SZ_BF;   // K head-major [b,h][l][d]
    ushort_t* vt   = (ushort_t*)(ws + off); off += SZ_BF;   // V transposed  [b,h][d][l]
    ushort_t* qo   = (ushort_t*)(ws + off); off += SZ_BF;   // q / attn-out / ffn1
    ushort_t* hb   = (ushort_t*)(ws + off); off += SZ_HBF;  // hidden bf16
    ushort_t* at1  = (ushort_t*)(ws + off); off += SZ_HBF;
    ushort_t* at2  = (ushort_t*)(ws + off); off += SZ_HBF;
    ushort_t* proj = (ushort_t*)(ws + off); off += SZ_HBF;
    ushort_t* WtQ  = (ushort_t*)(ws + off); off += SZ_WQKV;
    ushort_t* WtK  = (ushort_t*)(ws + off); off += SZ_WQKV;
    ushort_t* WtV  = (ushort_t*)(ws + off); off += SZ_WQKV;
    ushort_t* WtO  = (ushort_t*)(ws + off); off += SZ_WQKV;
    ushort_t* Wt1  = (ushort_t*)(ws + off); off += SZ_W12;
    ushort_t* Wt2  = (ushort_t*)(ws + off); off += SZ_W12;
    if (ws_size < off) return;  // total == 188,743,680 B (same as passing R3/R5-R11)
    ushort_t* ffn1 = qo;        // alias: qo free after out-proj2

    dim3 blk(256);
    cvt_f32_bf16<<<MROWS * HID / 1024, blk, 0, stream>>>(hidden, hb);
    wtrans<<<dim3(HD / 32, HID / 32), blk, 0, stream>>>(Wq, WtQ, HID, HD);
    wtrans<<<dim3(HD / 32, HID / 32), blk, 0, stream>>>(Wk, WtK, HID, HD);
    wtrans<<<dim3(HD / 32, HID / 32), blk, 0, stream>>>(Wv, WtV, HID, HD);
    wtrans<<<dim3(HID / 32, HD / 32), blk, 0, stream>>>(Wo, WtO, HD, HID);
    wtrans<<<dim3(4 * HID / 32, HID / 32), blk, 0, stream>>>(W1, Wt1, HID, 4 * HID);
    wtrans<<<dim3(HID / 32, 4 * HID / 32), blk, 0, stream>>>(W2, Wt2, 4 * HID, HID);

    const dim3 gProj(HD / 128, MROWS / 128);
    const dim3 gOut(HID / 128, MROWS / 128);
    const dim3 gF1(4 * HID / 128, MROWS / 128);

    // K head-major; V transposed head-major (shared by both MHAs)
    gemm_bt<false, 1, false><<<gProj, blk, 0, stream>>>(hb, WtK, bk, kb, MROWS, HD, HID);
    gemm_bt<false, 2, false><<<gProj, blk, 0, stream>>>(hb, WtV, bv, vt, MROWS, HD, HID);

    // MHA1 (Q pre-scaled by CSCALE)
    gemm_bt<false, 0, true><<<gProj, blk, 0, stream>>>(hb, WtQ, bq, qo, MROWS, HD, HID);
    attn_mfma16<<<2 * BATCH * NH, 512, 0, stream>>>(qo, kb, vt, qo);
    gemm_bt<false, 0, false><<<gOut, blk, 0, stream>>>(qo, WtO, bo, proj, MROWS, HID, HD);
    residual_ln<float, ushort_t><<<MROWS, blk, 0, stream>>>(proj, hidden, at1);

    // MHA2 (q from attn1; pooled K/V rebuilt from same kb/vt)
    gemm_bt<false, 0, true><<<gProj, blk, 0, stream>>>(at1, WtQ, bq, qo, MROWS, HD, HID);
    attn_mfma16<<<2 * BATCH * NH, 512, 0, stream>>>(qo, kb, vt, qo);
    gemm_bt<false, 0, false><<<gOut, blk, 0, stream>>>(qo, WtO, bo, proj, MROWS, HID, HD);
    residual_ln<ushort_t, ushort_t><<<MROWS, blk, 0, stream>>>(proj, at1, at2);

    // FFN
    gemm_bt<true, 0, false><<<gF1, blk, 0, stream>>>(at2, Wt1, b1, ffn1, MROWS, 4 * HID, HID);
    gemm_bt<false, 0, false><<<gOut, blk, 0, stream>>>(ffn1, Wt2, b2, proj, MROWS, HID, 4 * HID);
    residual_ln<ushort_t, float><<<MROWS, blk, 0, stream>>>(proj, at2, out);
}